// Round 2
// baseline (1028.074 us; speedup 1.0000x reference)
//
#include <hip/hip_runtime.h>
#include <hip/hip_bf16.h>

#define NN 100000
#define EE 800000
#define GG 1024
#define ETOT (EE + NN)

__device__ __forceinline__ float sigmoidf(float v) { return 1.f / (1.f + expf(-v)); }

// ---------------- init ----------------
__global__ void k_zero(int* deg, int* cur, float* gsum) {
    int i = blockIdx.x * 256 + threadIdx.x;
    if (i < NN) { deg[i] = 0; cur[i] = 0; }
    if (i < GG * 64) gsum[i] = 0.f;
}

// ---------------- CSR build ----------------
__global__ void k_hist(const int* __restrict__ ei, int* __restrict__ deg) {
    int e = blockIdx.x * 256 + threadIdx.x;
    if (e >= ETOT) return;
    int d = (e < EE) ? ei[EE + e] : (e - EE);
    atomicAdd(&deg[d], 1);
}

__global__ void k_scan1(const int* __restrict__ deg, int* __restrict__ offs,
                        int* __restrict__ bsum) {
    __shared__ int l[256];
    int i = blockIdx.x * 256 + threadIdx.x;
    l[threadIdx.x] = (i < NN) ? deg[i] : 0;
    __syncthreads();
    if (threadIdx.x == 0) {
        int run = 0;
        for (int j = 0; j < 256; j++) { int t = l[j]; l[j] = run; run += t; }
        bsum[blockIdx.x] = run;
    }
    __syncthreads();
    if (i < NN) offs[i] = l[threadIdx.x];
}

__global__ void k_scan2(int* __restrict__ bsum, int nb, int* __restrict__ offs) {
    if (blockIdx.x == 0 && threadIdx.x == 0) {
        int run = 0;
        for (int b = 0; b < nb; b++) { int t = bsum[b]; bsum[b] = run; run += t; }
        offs[NN] = run;
    }
}

__global__ void k_scan3(int* __restrict__ offs, const int* __restrict__ bsum) {
    int i = blockIdx.x * 256 + threadIdx.x;
    if (i < NN) offs[i] += bsum[blockIdx.x];
}

__global__ void k_scatter(const int* __restrict__ ei, const int* __restrict__ offs,
                          int* __restrict__ cur, int* __restrict__ csrc) {
    int e = blockIdx.x * 256 + threadIdx.x;
    if (e >= ETOT) return;
    int s, d;
    if (e < EE) { s = ei[e]; d = ei[EE + e]; }
    else { s = e - EE; d = e - EE; }
    int p = atomicAdd(&cur[d], 1);
    csrc[offs[d] + p] = s;
}

// ------- GEMM1 with fused embedding gather: C[N,256] = embed(x)[N,384] @ W1 -------
__global__ __launch_bounds__(256) void k_gemm1(const int* __restrict__ x,
                                               const float* __restrict__ e0,
                                               const float* __restrict__ e1,
                                               const float* __restrict__ e2,
                                               const float* __restrict__ e3,
                                               const float* __restrict__ e4,
                                               const float* __restrict__ e5,
                                               const float* __restrict__ B,
                                               float* __restrict__ C, int M) {
    __shared__ float As[16][68];
    __shared__ float Bs[16][64];
    int tid = threadIdx.x;
    int tx = tid & 15, ty = tid >> 4;
    int rowBase = blockIdx.y * 64;
    int colBase = blockIdx.x * 64;
    float acc[4][4] = {};
    for (int k0 = 0; k0 < 384; k0 += 16) {
        int t = k0 >> 6;                    // embedding table id, constant per step
        const float* tab = (t == 0) ? e0 : (t == 1) ? e1 : (t == 2) ? e2
                         : (t == 3) ? e3 : (t == 4) ? e4 : e5;
        int cb = k0 & 63;                   // column base within the table
#pragma unroll
        for (int l = 0; l < 4; l++) {
            int idx = tid + l * 256;
            int r = idx >> 4, kk = idx & 15;
            int row = rowBase + r;
            float v = 0.f;
            if (row < M) {
                int vi = x[row * 6 + t];
                v = tab[vi * 64 + cb + kk];
            }
            As[kk][r] = v;
        }
#pragma unroll
        for (int l = 0; l < 4; l++) {
            int idx = tid + l * 256;
            int c = idx & 63, kk = idx >> 6;
            Bs[kk][c] = B[(size_t)(k0 + kk) * 256 + colBase + c];
        }
        __syncthreads();
#pragma unroll
        for (int k = 0; k < 16; k++) {
            float4 av = *(const float4*)&As[k][ty * 4];
            float4 bv = *(const float4*)&Bs[k][tx * 4];
            float a_[4] = {av.x, av.y, av.z, av.w};
            float b_[4] = {bv.x, bv.y, bv.z, bv.w};
#pragma unroll
            for (int i = 0; i < 4; i++)
#pragma unroll
                for (int j = 0; j < 4; j++) acc[i][j] += a_[i] * b_[j];
        }
        __syncthreads();
    }
#pragma unroll
    for (int i = 0; i < 4; i++) {
        int row = rowBase + ty * 4 + i;
        if (row < M) {
            float4 v = make_float4(acc[i][0], acc[i][1], acc[i][2], acc[i][3]);
            *(float4*)&C[(size_t)row * 256 + colBase + tx * 4] = v;
        }
    }
}

// ---------------- f32 tiled GEMM: C[M,256] = A[M,K] @ B[K,256] ----------------
template <int K>
__global__ __launch_bounds__(256) void k_gemm(const float* __restrict__ A,
                                              const float* __restrict__ B,
                                              float* __restrict__ C, int M) {
    __shared__ float As[16][68];
    __shared__ float Bs[16][64];
    int tid = threadIdx.x;
    int tx = tid & 15, ty = tid >> 4;
    int rowBase = blockIdx.y * 64;
    int colBase = blockIdx.x * 64;
    float acc[4][4] = {};
    for (int k0 = 0; k0 < K; k0 += 16) {
#pragma unroll
        for (int l = 0; l < 4; l++) {
            int idx = tid + l * 256;
            int r = idx >> 4, kk = idx & 15;
            int row = rowBase + r;
            As[kk][r] = (row < M) ? A[(size_t)row * K + k0 + kk] : 0.f;
        }
#pragma unroll
        for (int l = 0; l < 4; l++) {
            int idx = tid + l * 256;
            int c = idx & 63, kk = idx >> 6;
            Bs[kk][c] = B[(size_t)(k0 + kk) * 256 + colBase + c];
        }
        __syncthreads();
#pragma unroll
        for (int k = 0; k < 16; k++) {
            float4 av = *(const float4*)&As[k][ty * 4];
            float4 bv = *(const float4*)&Bs[k][tx * 4];
            float a_[4] = {av.x, av.y, av.z, av.w};
            float b_[4] = {bv.x, bv.y, bv.z, bv.w};
#pragma unroll
            for (int i = 0; i < 4; i++)
#pragma unroll
                for (int j = 0; j < 4; j++) acc[i][j] += a_[i] * b_[j];
        }
        __syncthreads();
    }
#pragma unroll
    for (int i = 0; i < 4; i++) {
        int row = rowBase + ty * 4 + i;
        if (row < M) {
            float4 v = make_float4(acc[i][0], acc[i][1], acc[i][2], acc[i][3]);
            *(float4*)&C[(size_t)row * 256 + colBase + tx * 4] = v;
        }
    }
}

// ---------------- per-(node,head) attention dots ----------------
template <int H, int C>
__global__ void k_sd(const float* __restrict__ xw, const float* __restrict__ a_src,
                     const float* __restrict__ a_dst, float* __restrict__ s,
                     float* __restrict__ dv) {
    int gtid = blockIdx.x * 256 + threadIdx.x;
    int wid = gtid >> 6;
    int lane = threadIdx.x & 63;
    if (wid >= NN * H) return;
    int n = wid / H, h = wid % H;
    const float* base = xw + (size_t)n * H * C + h * C;
    float vs = 0.f, vd = 0.f;
    for (int c = lane; c < C; c += 64) {
        float v = base[c];
        vs += v * a_src[h * C + c];
        vd += v * a_dst[h * C + c];
    }
    for (int o = 32; o; o >>= 1) { vs += __shfl_down(vs, o); vd += __shfl_down(vd, o); }
    if (lane == 0) { s[wid] = vs; dv[wid] = vd; }
}

// ------- layer-1 aggregation fused with head-mean+bias+sigmoid -> h1[N,128] -------
__global__ void k_agg1(const float* __restrict__ xw, const float* __restrict__ s,
                       const float* __restrict__ dvec, const int* __restrict__ offs,
                       const int* __restrict__ csrc, const float* __restrict__ b1,
                       float* __restrict__ h1) {
    __shared__ float tmp[128];
    int n = blockIdx.x;
    int h = threadIdx.x >> 6;
    int lane = threadIdx.x & 63;
    int start = offs[n], end = offs[n + 1];
    float dn = dvec[n * 2 + h];
    float m = -1e30f;
    for (int i = start + lane; i < end; i += 64) {
        float e = s[csrc[i] * 2 + h] + dn;
        e = (e > 0.f) ? e : 0.2f * e;
        m = fmaxf(m, e);
    }
    for (int o = 32; o; o >>= 1) m = fmaxf(m, __shfl_xor(m, o));
    float denom = 0.f, acc0 = 0.f, acc1 = 0.f;
    for (int ch = start; ch < end; ch += 64) {
        int i = ch + lane;
        float w = 0.f;
        int sn = 0;
        if (i < end) {
            sn = csrc[i];
            float e = s[sn * 2 + h] + dn;
            e = (e > 0.f) ? e : 0.2f * e;
            w = expf(e - m);
        }
        int cnt = min(64, end - ch);
        for (int j = 0; j < cnt; j++) {
            float wj = __shfl(w, j);
            int snj = __shfl(sn, j);
            denom += wj;
            const float* src = xw + (size_t)snj * 256 + h * 128 + lane;
            acc0 += wj * src[0];
            acc1 += wj * src[64];
        }
    }
    float inv = 1.f / (denom + 1e-16f);
    acc0 *= inv; acc1 *= inv;
    if (h == 1) { tmp[lane] = acc0; tmp[64 + lane] = acc1; }
    __syncthreads();
    if (h == 0) {
        h1[(size_t)n * 128 + lane]      = sigmoidf(0.5f * (acc0 + tmp[lane]) + b1[lane]);
        h1[(size_t)n * 128 + 64 + lane] = sigmoidf(0.5f * (acc1 + tmp[64 + lane]) + b1[64 + lane]);
    }
}

// ------- layer-2 aggregation fused with head-mean+bias+sigmoid+global pool -------
__global__ void k_agg2(const float* __restrict__ xw, const float* __restrict__ s,
                       const float* __restrict__ dvec, const int* __restrict__ offs,
                       const int* __restrict__ csrc, const float* __restrict__ b2,
                       const int* __restrict__ batch, float* __restrict__ gsum) {
    __shared__ float tmp[4][64];
    int n = blockIdx.x;
    int h = threadIdx.x >> 6;
    int lane = threadIdx.x & 63;
    int start = offs[n], end = offs[n + 1];
    float dn = dvec[n * 4 + h];
    float m = -1e30f;
    for (int i = start + lane; i < end; i += 64) {
        float e = s[csrc[i] * 4 + h] + dn;
        e = (e > 0.f) ? e : 0.2f * e;
        m = fmaxf(m, e);
    }
    for (int o = 32; o; o >>= 1) m = fmaxf(m, __shfl_xor(m, o));
    float denom = 0.f, acc = 0.f;
    for (int ch = start; ch < end; ch += 64) {
        int i = ch + lane;
        float w = 0.f;
        int sn = 0;
        if (i < end) {
            sn = csrc[i];
            float e = s[sn * 4 + h] + dn;
            e = (e > 0.f) ? e : 0.2f * e;
            w = expf(e - m);
        }
        int cnt = min(64, end - ch);
        for (int j = 0; j < cnt; j++) {
            float wj = __shfl(w, j);
            int snj = __shfl(sn, j);
            denom += wj;
            acc += wj * xw[(size_t)snj * 256 + h * 64 + lane];
        }
    }
    tmp[h][lane] = acc / (denom + 1e-16f);
    __syncthreads();
    if (h == 0) {
        float v = 0.25f * (tmp[0][lane] + tmp[1][lane] + tmp[2][lane] + tmp[3][lane]) + b2[lane];
        atomicAdd(&gsum[batch[n] * 64 + lane], sigmoidf(v));
    }
}

// ---------------- final ----------------
__global__ void k_final(const float* __restrict__ gsum, const float* __restrict__ lw,
                        const float* __restrict__ lb, float* __restrict__ out) {
    int g = blockIdx.x;
    int lane = threadIdx.x;
    float v = gsum[g * 64 + lane] * lw[lane];
    for (int o = 32; o; o >>= 1) v += __shfl_down(v, o);
    if (lane == 0) out[g] = sigmoidf(v + lb[0]);
}

// ---------------- launch ----------------
extern "C" void kernel_launch(void* const* d_in, const int* in_sizes, int n_in,
                              void* d_out, int out_size, void* d_ws, size_t ws_size,
                              hipStream_t stream) {
    const int* x   = (const int*)d_in[0];
    const int* ei  = (const int*)d_in[1];
    const int* bat = (const int*)d_in[3];
    const float* e0 = (const float*)d_in[4];
    const float* e1 = (const float*)d_in[5];
    const float* e2 = (const float*)d_in[6];
    const float* e3 = (const float*)d_in[7];
    const float* e4 = (const float*)d_in[8];
    const float* e5 = (const float*)d_in[9];
    const float* W1 = (const float*)d_in[10];
    const float* as1 = (const float*)d_in[11];
    const float* ad1 = (const float*)d_in[12];
    const float* b1 = (const float*)d_in[13];
    const float* W2 = (const float*)d_in[14];
    const float* as2 = (const float*)d_in[15];
    const float* ad2 = (const float*)d_in[16];
    const float* b2 = (const float*)d_in[17];
    const float* lw = (const float*)d_in[18];
    const float* lb = (const float*)d_in[19];
    float* out = (float*)d_out;

    char* base = (char*)d_ws;
    size_t off = 0;
    auto alloc = [&](size_t bytes) {
        size_t o = off;
        off = (off + bytes + 255) & ~(size_t)255;
        return o;
    };
    float* buf1 = (float*)(base + alloc((size_t)NN * 256 * 4));  // xw1 then xw2
    float* h1   = (float*)(base + alloc((size_t)NN * 128 * 4));  // layer-1 output
    float* sbuf = (float*)(base + alloc((size_t)NN * 4 * 4));
    float* dbuf = (float*)(base + alloc((size_t)NN * 4 * 4));
    float* gsum = (float*)(base + alloc((size_t)GG * 64 * 4));
    int* deg  = (int*)(base + alloc((size_t)NN * 4));
    int* offs = (int*)(base + alloc((size_t)(NN + 1) * 4));
    int* cur  = (int*)(base + alloc((size_t)NN * 4));
    int* csrc = (int*)(base + alloc((size_t)ETOT * 4));
    int* bsum = (int*)(base + alloc((size_t)512 * 4));

    const int nb = (NN + 255) / 256;  // 391

    k_zero<<<nb, 256, 0, stream>>>(deg, cur, gsum);
    k_hist<<<(ETOT + 255) / 256, 256, 0, stream>>>(ei, deg);
    k_scan1<<<nb, 256, 0, stream>>>(deg, offs, bsum);
    k_scan2<<<1, 64, 0, stream>>>(bsum, nb, offs);
    k_scan3<<<nb, 256, 0, stream>>>(offs, bsum);
    k_scatter<<<(ETOT + 255) / 256, 256, 0, stream>>>(ei, offs, cur, csrc);

    // layer 1
    {
        dim3 grid(4, (NN + 63) / 64);
        k_gemm1<<<grid, 256, 0, stream>>>(x, e0, e1, e2, e3, e4, e5, W1, buf1, NN);
    }
    k_sd<2, 128><<<(NN * 2 * 64) / 256, 256, 0, stream>>>(buf1, as1, ad1, sbuf, dbuf);
    k_agg1<<<NN, 128, 0, stream>>>(buf1, sbuf, dbuf, offs, csrc, b1, h1);

    // layer 2
    {
        dim3 grid(4, (NN + 63) / 64);
        k_gemm<128><<<grid, 256, 0, stream>>>(h1, W2, buf1, NN);
    }
    k_sd<4, 64><<<(NN * 4 * 64) / 256, 256, 0, stream>>>(buf1, as2, ad2, sbuf, dbuf);
    k_agg2<<<NN, 256, 0, stream>>>(buf1, sbuf, dbuf, offs, csrc, b2, bat, gsum);

    // final
    k_final<<<GG, 64, 0, stream>>>(gsum, lw, lb, out);
}

// Round 3
// 702.793 us; speedup vs baseline: 1.4628x; 1.4628x over previous
//
#include <hip/hip_runtime.h>
#include <hip/hip_bf16.h>

#define NN 100000
#define EE 800000
#define GG 1024
#define ETOT (EE + NN)

typedef __attribute__((ext_vector_type(8))) short short8;
typedef __attribute__((ext_vector_type(4))) float floatx4;

__device__ __forceinline__ float sigmoidf_(float v) { return 1.f / (1.f + expf(-v)); }
__device__ __forceinline__ float bf2f(unsigned short u) {
    union { unsigned int i; float f; } x; x.i = ((unsigned int)u) << 16; return x.f;
}
__device__ __forceinline__ unsigned short f2bf(float f) {
    union { unsigned int i; float f; } x; x.f = f;
    unsigned int r = (x.i + 0x7fff + ((x.i >> 16) & 1)) >> 16;
    return (unsigned short)r;
}

// ---------------- init ----------------
__global__ void k_zero(int* deg, int* cur, float* gsum) {
    int i = blockIdx.x * 256 + threadIdx.x;
    if (i < NN) { deg[i] = 0; cur[i] = 0; }
    if (i < GG * 64) gsum[i] = 0.f;
}

// ---------------- precompute: embeddings + weights -> bf16 ----------------
__global__ void k_prep_emb(const float* __restrict__ e0, const float* __restrict__ e1,
                           const float* __restrict__ e2, const float* __restrict__ e3,
                           const float* __restrict__ e4, const float* __restrict__ e5,
                           unsigned short* __restrict__ ebf) {
    int i = blockIdx.x * 256 + threadIdx.x;
    if (i >= 50 * 64) return;
    int row = i >> 6, c = i & 63;
    const float* tab; int r;
    if (row < 33)      { tab = e0; r = row; }
    else if (row < 38) { tab = e1; r = row - 33; }
    else if (row < 41) { tab = e2; r = row - 38; }
    else if (row < 45) { tab = e3; r = row - 41; }
    else if (row < 47) { tab = e4; r = row - 45; }
    else               { tab = e5; r = row - 47; }
    ebf[i] = f2bf(tab[r * 64 + c]);
}

// W [K][256] f32 -> frag-ordered bf16: Wt[((ks*16+cf)*64 + lane)*8 + j]
// where k = ks*32 + (lane>>4)*8 + j, col = cf*16 + (lane&15)
template <int KS>
__global__ void k_prep_w(const float* __restrict__ W, unsigned short* __restrict__ Wt) {
    int tid = blockIdx.x * 256 + threadIdx.x;
    if (tid >= KS * 16 * 64) return;
    int l = tid & 63;
    int cf = (tid >> 6) & 15;
    int ks = tid >> 10;
    int kbase = ks * 32 + (l >> 4) * 8;
    int col = cf * 16 + (l & 15);
    unsigned short* o = Wt + (size_t)tid * 8;
#pragma unroll
    for (int j = 0; j < 8; j++) o[j] = f2bf(W[(size_t)(kbase + j) * 256 + col]);
}

// ---------------- CSR build ----------------
__global__ void k_hist(const int* __restrict__ ei, int* __restrict__ deg) {
    int e = blockIdx.x * 256 + threadIdx.x;
    if (e >= ETOT) return;
    int d = (e < EE) ? ei[EE + e] : (e - EE);
    atomicAdd(&deg[d], 1);
}

__global__ void k_scan1(const int* __restrict__ deg, int* __restrict__ offs,
                        int* __restrict__ bsum) {
    __shared__ int l[256];
    int i = blockIdx.x * 256 + threadIdx.x;
    l[threadIdx.x] = (i < NN) ? deg[i] : 0;
    __syncthreads();
    if (threadIdx.x == 0) {
        int run = 0;
        for (int j = 0; j < 256; j++) { int t = l[j]; l[j] = run; run += t; }
        bsum[blockIdx.x] = run;
    }
    __syncthreads();
    if (i < NN) offs[i] = l[threadIdx.x];
}

// wave-parallel scan over block sums
__global__ void k_scan2(int* __restrict__ bsum, int nb, int* __restrict__ offs) {
    int lane = threadIdx.x;  // 64 threads
    int run = 0;
    for (int base = 0; base < nb; base += 64) {
        int i = base + lane;
        int orig = (i < nb) ? bsum[i] : 0;
        int v = orig;
#pragma unroll
        for (int o = 1; o < 64; o <<= 1) {
            int t = __shfl_up(v, o);
            if (lane >= o) v += t;
        }
        if (i < nb) bsum[i] = run + v - orig;   // exclusive
        run += __shfl(v, 63);
    }
    if (lane == 0) offs[NN] = run;
}

__global__ void k_scan3(int* __restrict__ offs, const int* __restrict__ bsum) {
    int i = blockIdx.x * 256 + threadIdx.x;
    if (i < NN) offs[i] += bsum[blockIdx.x];
}

__global__ void k_scatter(const int* __restrict__ ei, const int* __restrict__ offs,
                          int* __restrict__ cur, int* __restrict__ csrc) {
    int e = blockIdx.x * 256 + threadIdx.x;
    if (e >= ETOT) return;
    int s, d;
    if (e < EE) { s = ei[e]; d = ei[EE + e]; }
    else { s = e - EE; d = e - EE; }
    int p = atomicAdd(&cur[d], 1);
    csrc[offs[d] + p] = s;
}

// ---------------- bf16 MFMA GEMM: C[M,256] = A[M,K] @ W[K,256] ----------------
// MODE 0: A = embedding gather (K=384); MODE 1: A = h1 bf16 [M,128] (K=128)
template <int MODE, int KSTEPS>
__global__ __launch_bounds__(256) void k_gemm_mfma(const int* __restrict__ x,
                                                   const unsigned short* __restrict__ ebf,
                                                   const unsigned short* __restrict__ Abf,
                                                   const unsigned short* __restrict__ Wt,
                                                   unsigned short* __restrict__ Cb, int M) {
    __shared__ __align__(16) unsigned short As[128 * 40];  // rows padded to 40 bf16 (80B)
    int tid = threadIdx.x;
    int rowBase = blockIdx.y * 128;
    int colBase = blockIdx.x * 64;
    int l = tid & 63, w = tid >> 6;
    int strip = w * 32;
    floatx4 acc[2][4] = {};

    for (int ks = 0; ks < KSTEPS; ks++) {
        // stage A tile [128 rows][32 k] bf16
        {
            int r = tid >> 1, half = tid & 1;
            int row = rowBase + r;
            uint4 v0 = {0, 0, 0, 0}, v1 = {0, 0, 0, 0};
            if (row < M) {
                const unsigned short* src;
                if (MODE == 0) {
                    int t = ks >> 1, cb = (ks & 1) * 32;
                    int toff = (t == 0) ? 0 : (t == 1) ? 33 : (t == 2) ? 38
                             : (t == 3) ? 41 : (t == 4) ? 45 : 47;
                    int vi = x[row * 6 + t];
                    src = ebf + (size_t)(toff + vi) * 64 + cb + half * 16;
                } else {
                    src = Abf + (size_t)row * 128 + ks * 32 + half * 16;
                }
                v0 = *(const uint4*)src;
                v1 = *(const uint4*)(src + 8);
            }
            uint4* dst = (uint4*)&As[r * 40 + half * 16];
            dst[0] = v0; dst[1] = v1;
        }
        __syncthreads();
        short8 a0 = *(const short8*)&As[(strip + (l & 15)) * 40 + (l >> 4) * 8];
        short8 a1 = *(const short8*)&As[(strip + 16 + (l & 15)) * 40 + (l >> 4) * 8];
        const short8* bp = (const short8*)(Wt + ((size_t)(ks * 16 + (colBase >> 4)) * 64 + l) * 8);
#pragma unroll
        for (int cf = 0; cf < 4; cf++) {
            short8 b = bp[cf * 64];
            acc[0][cf] = __builtin_amdgcn_mfma_f32_16x16x32_bf16(a0, b, acc[0][cf], 0, 0, 0);
            acc[1][cf] = __builtin_amdgcn_mfma_f32_16x16x32_bf16(a1, b, acc[1][cf], 0, 0, 0);
        }
        __syncthreads();
    }
#pragma unroll
    for (int rf = 0; rf < 2; rf++)
#pragma unroll
        for (int cf = 0; cf < 4; cf++)
#pragma unroll
            for (int i = 0; i < 4; i++) {
                int row = rowBase + strip + rf * 16 + (l >> 4) * 4 + i;
                int col = colBase + cf * 16 + (l & 15);
                if (row < M) Cb[(size_t)row * 256 + col] = f2bf(acc[rf][cf][i]);
            }
}

// ---------------- per-(node,head) attention dots (bf16 xw) ----------------
template <int H, int C>
__global__ void k_sd(const unsigned short* __restrict__ xwb, const float* __restrict__ a_src,
                     const float* __restrict__ a_dst, float* __restrict__ s,
                     float* __restrict__ dv) {
    int gtid = blockIdx.x * 256 + threadIdx.x;
    int wid = gtid >> 6;
    int lane = threadIdx.x & 63;
    if (wid >= NN * H) return;
    int n = wid / H, h = wid % H;
    const unsigned short* base = xwb + (size_t)n * H * C + h * C;
    float vs = 0.f, vd = 0.f;
    for (int c = lane; c < C; c += 64) {
        float v = bf2f(base[c]);
        vs += v * a_src[h * C + c];
        vd += v * a_dst[h * C + c];
    }
    for (int o = 32; o; o >>= 1) { vs += __shfl_down(vs, o); vd += __shfl_down(vd, o); }
    if (lane == 0) { s[wid] = vs; dv[wid] = vd; }
}

// ------- layer-1 aggregation fused with head-mean+bias+sigmoid -> h1 bf16 -------
__global__ void k_agg1(const unsigned short* __restrict__ xwb, const float* __restrict__ s,
                       const float* __restrict__ dvec, const int* __restrict__ offs,
                       const int* __restrict__ csrc, const float* __restrict__ b1,
                       unsigned short* __restrict__ h1b) {
    __shared__ float tmp[128];
    int n = blockIdx.x;
    int h = threadIdx.x >> 6;
    int lane = threadIdx.x & 63;
    int start = offs[n], end = offs[n + 1];
    float dn = dvec[n * 2 + h];
    float m = -1e30f;
    for (int i = start + lane; i < end; i += 64) {
        float e = s[csrc[i] * 2 + h] + dn;
        e = (e > 0.f) ? e : 0.2f * e;
        m = fmaxf(m, e);
    }
    for (int o = 32; o; o >>= 1) m = fmaxf(m, __shfl_xor(m, o));
    float denom = 0.f, acc0 = 0.f, acc1 = 0.f;
    for (int ch = start; ch < end; ch += 64) {
        int i = ch + lane;
        float w = 0.f;
        int sn = 0;
        if (i < end) {
            sn = csrc[i];
            float e = s[sn * 2 + h] + dn;
            e = (e > 0.f) ? e : 0.2f * e;
            w = expf(e - m);
        }
        int cnt = min(64, end - ch);
        for (int j = 0; j < cnt; j++) {
            float wj = __shfl(w, j);
            int snj = __shfl(sn, j);
            denom += wj;
            const unsigned short* src = xwb + (size_t)snj * 256 + h * 128 + lane;
            acc0 += wj * bf2f(src[0]);
            acc1 += wj * bf2f(src[64]);
        }
    }
    float inv = 1.f / (denom + 1e-16f);
    acc0 *= inv; acc1 *= inv;
    if (h == 1) { tmp[lane] = acc0; tmp[64 + lane] = acc1; }
    __syncthreads();
    if (h == 0) {
        h1b[(size_t)n * 128 + lane] =
            f2bf(sigmoidf_(0.5f * (acc0 + tmp[lane]) + b1[lane]));
        h1b[(size_t)n * 128 + 64 + lane] =
            f2bf(sigmoidf_(0.5f * (acc1 + tmp[64 + lane]) + b1[64 + lane]));
    }
}

// ------- layer-2 aggregation fused with head-mean+bias+sigmoid+pool -------
__global__ void k_agg2(const unsigned short* __restrict__ xwb, const float* __restrict__ s,
                       const float* __restrict__ dvec, const int* __restrict__ offs,
                       const int* __restrict__ csrc, const float* __restrict__ b2,
                       const int* __restrict__ batch, float* __restrict__ gsum) {
    __shared__ float tmp[4][64];
    int n = blockIdx.x;
    int h = threadIdx.x >> 6;
    int lane = threadIdx.x & 63;
    int start = offs[n], end = offs[n + 1];
    float dn = dvec[n * 4 + h];
    float m = -1e30f;
    for (int i = start + lane; i < end; i += 64) {
        float e = s[csrc[i] * 4 + h] + dn;
        e = (e > 0.f) ? e : 0.2f * e;
        m = fmaxf(m, e);
    }
    for (int o = 32; o; o >>= 1) m = fmaxf(m, __shfl_xor(m, o));
    float denom = 0.f, acc = 0.f;
    for (int ch = start; ch < end; ch += 64) {
        int i = ch + lane;
        float w = 0.f;
        int sn = 0;
        if (i < end) {
            sn = csrc[i];
            float e = s[sn * 4 + h] + dn;
            e = (e > 0.f) ? e : 0.2f * e;
            w = expf(e - m);
        }
        int cnt = min(64, end - ch);
        for (int j = 0; j < cnt; j++) {
            float wj = __shfl(w, j);
            int snj = __shfl(sn, j);
            denom += wj;
            acc += wj * bf2f(xwb[(size_t)snj * 256 + h * 64 + lane]);
        }
    }
    tmp[h][lane] = acc / (denom + 1e-16f);
    __syncthreads();
    if (h == 0) {
        float v = 0.25f * (tmp[0][lane] + tmp[1][lane] + tmp[2][lane] + tmp[3][lane]) + b2[lane];
        atomicAdd(&gsum[batch[n] * 64 + lane], sigmoidf_(v));
    }
}

// ---------------- final ----------------
__global__ void k_final(const float* __restrict__ gsum, const float* __restrict__ lw,
                        const float* __restrict__ lb, float* __restrict__ out) {
    int g = blockIdx.x;
    int lane = threadIdx.x;
    float v = gsum[g * 64 + lane] * lw[lane];
    for (int o = 32; o; o >>= 1) v += __shfl_down(v, o);
    if (lane == 0) out[g] = sigmoidf_(v + lb[0]);
}

// ---------------- launch ----------------
extern "C" void kernel_launch(void* const* d_in, const int* in_sizes, int n_in,
                              void* d_out, int out_size, void* d_ws, size_t ws_size,
                              hipStream_t stream) {
    const int* x   = (const int*)d_in[0];
    const int* ei  = (const int*)d_in[1];
    const int* bat = (const int*)d_in[3];
    const float* e0 = (const float*)d_in[4];
    const float* e1 = (const float*)d_in[5];
    const float* e2 = (const float*)d_in[6];
    const float* e3 = (const float*)d_in[7];
    const float* e4 = (const float*)d_in[8];
    const float* e5 = (const float*)d_in[9];
    const float* W1 = (const float*)d_in[10];
    const float* as1 = (const float*)d_in[11];
    const float* ad1 = (const float*)d_in[12];
    const float* b1 = (const float*)d_in[13];
    const float* W2 = (const float*)d_in[14];
    const float* as2 = (const float*)d_in[15];
    const float* ad2 = (const float*)d_in[16];
    const float* b2 = (const float*)d_in[17];
    const float* lw = (const float*)d_in[18];
    const float* lb = (const float*)d_in[19];
    float* out = (float*)d_out;

    char* base = (char*)d_ws;
    size_t off = 0;
    auto alloc = [&](size_t bytes) {
        size_t o = off;
        off = (off + bytes + 255) & ~(size_t)255;
        return o;
    };
    unsigned short* xwb = (unsigned short*)(base + alloc((size_t)NN * 256 * 2));
    unsigned short* h1b = (unsigned short*)(base + alloc((size_t)NN * 128 * 2));
    float* sbuf = (float*)(base + alloc((size_t)NN * 4 * 4));
    float* dbuf = (float*)(base + alloc((size_t)NN * 4 * 4));
    float* gsum = (float*)(base + alloc((size_t)GG * 64 * 4));
    int* deg  = (int*)(base + alloc((size_t)NN * 4));
    int* offs = (int*)(base + alloc((size_t)(NN + 1) * 4));
    int* cur  = (int*)(base + alloc((size_t)NN * 4));
    int* csrc = (int*)(base + alloc((size_t)ETOT * 4));
    int* bsum = (int*)(base + alloc((size_t)512 * 4));
    unsigned short* ebf = (unsigned short*)(base + alloc((size_t)50 * 64 * 2));
    unsigned short* Wt1 = (unsigned short*)(base + alloc((size_t)384 * 256 * 2));
    unsigned short* Wt2 = (unsigned short*)(base + alloc((size_t)128 * 256 * 2));

    const int nb = (NN + 255) / 256;  // 391

    k_zero<<<nb, 256, 0, stream>>>(deg, cur, gsum);
    k_prep_emb<<<(50 * 64 + 255) / 256, 256, 0, stream>>>(e0, e1, e2, e3, e4, e5, ebf);
    k_prep_w<12><<<(12 * 16 * 64 + 255) / 256, 256, 0, stream>>>(W1, Wt1);
    k_prep_w<4><<<(4 * 16 * 64 + 255) / 256, 256, 0, stream>>>(W2, Wt2);
    k_hist<<<(ETOT + 255) / 256, 256, 0, stream>>>(ei, deg);
    k_scan1<<<nb, 256, 0, stream>>>(deg, offs, bsum);
    k_scan2<<<1, 64, 0, stream>>>(bsum, nb, offs);
    k_scan3<<<nb, 256, 0, stream>>>(offs, bsum);
    k_scatter<<<(ETOT + 255) / 256, 256, 0, stream>>>(ei, offs, cur, csrc);

    // layer 1
    {
        dim3 grid(4, (NN + 127) / 128);
        k_gemm_mfma<0, 12><<<grid, 256, 0, stream>>>(x, ebf, nullptr, Wt1, xwb, NN);
    }
    k_sd<2, 128><<<(NN * 2 * 64) / 256, 256, 0, stream>>>(xwb, as1, ad1, sbuf, dbuf);
    k_agg1<<<NN, 128, 0, stream>>>(xwb, sbuf, dbuf, offs, csrc, b1, h1b);

    // layer 2
    {
        dim3 grid(4, (NN + 127) / 128);
        k_gemm_mfma<1, 4><<<grid, 256, 0, stream>>>(x, ebf, h1b, Wt2, xwb, NN);
    }
    k_sd<4, 64><<<(NN * 4 * 64) / 256, 256, 0, stream>>>(xwb, as2, ad2, sbuf, dbuf);
    k_agg2<<<NN, 256, 0, stream>>>(xwb, sbuf, dbuf, offs, csrc, b2, bat, gsum);

    // final
    k_final<<<GG, 64, 0, stream>>>(gsum, lw, lb, out);
}

// Round 4
// 523.114 us; speedup vs baseline: 1.9653x; 1.3435x over previous
//
#include <hip/hip_runtime.h>
#include <hip/hip_bf16.h>

#define NN 100000
#define EE 800000
#define GG 1024
#define ETOT (EE + NN)

typedef __attribute__((ext_vector_type(8))) short short8;
typedef __attribute__((ext_vector_type(4))) float floatx4;

__device__ __forceinline__ float sigmoidf_(float v) { return 1.f / (1.f + expf(-v)); }
__device__ __forceinline__ float bf2f(unsigned short u) {
    union { unsigned int i; float f; } x; x.i = ((unsigned int)u) << 16; return x.f;
}
__device__ __forceinline__ unsigned short f2bf(float f) {
    union { unsigned int i; float f; } x; x.f = f;
    unsigned int r = (x.i + 0x7fff + ((x.i >> 16) & 1)) >> 16;
    return (unsigned short)r;
}

// ---------------- init ----------------
__global__ void k_zero(int* deg, int* cur, float* gsum) {
    int i = blockIdx.x * 256 + threadIdx.x;
    if (i < NN) { deg[i] = 0; cur[i] = 0; }
    if (i < GG * 64) gsum[i] = 0.f;
}

// ---------------- precompute: embeddings + weights -> bf16 ----------------
__global__ void k_prep_emb(const float* __restrict__ e0, const float* __restrict__ e1,
                           const float* __restrict__ e2, const float* __restrict__ e3,
                           const float* __restrict__ e4, const float* __restrict__ e5,
                           unsigned short* __restrict__ ebf) {
    int i = blockIdx.x * 256 + threadIdx.x;
    if (i >= 50 * 64) return;
    int row = i >> 6, c = i & 63;
    const float* tab; int r;
    if (row < 33)      { tab = e0; r = row; }
    else if (row < 38) { tab = e1; r = row - 33; }
    else if (row < 41) { tab = e2; r = row - 38; }
    else if (row < 45) { tab = e3; r = row - 41; }
    else if (row < 47) { tab = e4; r = row - 45; }
    else               { tab = e5; r = row - 47; }
    ebf[i] = f2bf(tab[r * 64 + c]);
}

// W [K][256] f32 -> frag-ordered bf16: Wt[((ks*16+cf)*64 + lane)*8 + j]
template <int KS>
__global__ void k_prep_w(const float* __restrict__ W, unsigned short* __restrict__ Wt) {
    int tid = blockIdx.x * 256 + threadIdx.x;
    if (tid >= KS * 16 * 64) return;
    int l = tid & 63;
    int cf = (tid >> 6) & 15;
    int ks = tid >> 10;
    int kbase = ks * 32 + (l >> 4) * 8;
    int col = cf * 16 + (l & 15);
    unsigned short* o = Wt + (size_t)tid * 8;
#pragma unroll
    for (int j = 0; j < 8; j++) o[j] = f2bf(W[(size_t)(kbase + j) * 256 + col]);
}

// ---------------- CSR build ----------------
__global__ void k_hist(const int* __restrict__ ei, int* __restrict__ deg) {
    int e = blockIdx.x * 256 + threadIdx.x;
    if (e >= ETOT) return;
    int d = (e < EE) ? ei[EE + e] : (e - EE);
    atomicAdd(&deg[d], 1);
}

__global__ void k_scan1(const int* __restrict__ deg, int* __restrict__ offs,
                        int* __restrict__ bsum) {
    __shared__ int l[256];
    int i = blockIdx.x * 256 + threadIdx.x;
    l[threadIdx.x] = (i < NN) ? deg[i] : 0;
    __syncthreads();
    if (threadIdx.x == 0) {
        int run = 0;
        for (int j = 0; j < 256; j++) { int t = l[j]; l[j] = run; run += t; }
        bsum[blockIdx.x] = run;
    }
    __syncthreads();
    if (i < NN) offs[i] = l[threadIdx.x];
}

__global__ void k_scan2(int* __restrict__ bsum, int nb, int* __restrict__ offs) {
    int lane = threadIdx.x;  // 64 threads
    int run = 0;
    for (int base = 0; base < nb; base += 64) {
        int i = base + lane;
        int orig = (i < nb) ? bsum[i] : 0;
        int v = orig;
#pragma unroll
        for (int o = 1; o < 64; o <<= 1) {
            int t = __shfl_up(v, o);
            if (lane >= o) v += t;
        }
        if (i < nb) bsum[i] = run + v - orig;   // exclusive
        run += __shfl(v, 63);
    }
    if (lane == 0) offs[NN] = run;
}

__global__ void k_scan3(int* __restrict__ offs, const int* __restrict__ bsum) {
    int i = blockIdx.x * 256 + threadIdx.x;
    if (i < NN) offs[i] += bsum[blockIdx.x];
}

__global__ void k_scatter(const int* __restrict__ ei, const int* __restrict__ offs,
                          int* __restrict__ cur, int* __restrict__ csrc) {
    int e = blockIdx.x * 256 + threadIdx.x;
    if (e >= ETOT) return;
    int s, d;
    if (e < EE) { s = ei[e]; d = ei[EE + e]; }
    else { s = e - EE; d = e - EE; }
    int p = atomicAdd(&cur[d], 1);
    csrc[offs[d] + p] = s;
}

// ---------------- bf16 MFMA GEMM: C[M,256] = A[M,K] @ W[K,256] ----------------
template <int MODE, int KSTEPS>
__global__ __launch_bounds__(256) void k_gemm_mfma(const int* __restrict__ x,
                                                   const unsigned short* __restrict__ ebf,
                                                   const unsigned short* __restrict__ Abf,
                                                   const unsigned short* __restrict__ Wt,
                                                   unsigned short* __restrict__ Cb, int M) {
    __shared__ __align__(16) unsigned short As[128 * 40];
    int tid = threadIdx.x;
    int rowBase = blockIdx.y * 128;
    int colBase = blockIdx.x * 64;
    int l = tid & 63, w = tid >> 6;
    int strip = w * 32;
    floatx4 acc[2][4] = {};

    for (int ks = 0; ks < KSTEPS; ks++) {
        {
            int r = tid >> 1, half = tid & 1;
            int row = rowBase + r;
            uint4 v0 = {0, 0, 0, 0}, v1 = {0, 0, 0, 0};
            if (row < M) {
                const unsigned short* src;
                if (MODE == 0) {
                    int t = ks >> 1, cb = (ks & 1) * 32;
                    int toff = (t == 0) ? 0 : (t == 1) ? 33 : (t == 2) ? 38
                             : (t == 3) ? 41 : (t == 4) ? 45 : 47;
                    int vi = x[row * 6 + t];
                    src = ebf + (size_t)(toff + vi) * 64 + cb + half * 16;
                } else {
                    src = Abf + (size_t)row * 128 + ks * 32 + half * 16;
                }
                v0 = *(const uint4*)src;
                v1 = *(const uint4*)(src + 8);
            }
            uint4* dst = (uint4*)&As[r * 40 + half * 16];
            dst[0] = v0; dst[1] = v1;
        }
        __syncthreads();
        short8 a0 = *(const short8*)&As[(strip + (l & 15)) * 40 + (l >> 4) * 8];
        short8 a1 = *(const short8*)&As[(strip + 16 + (l & 15)) * 40 + (l >> 4) * 8];
        const short8* bp = (const short8*)(Wt + ((size_t)(ks * 16 + (colBase >> 4)) * 64 + l) * 8);
#pragma unroll
        for (int cf = 0; cf < 4; cf++) {
            short8 b = bp[cf * 64];
            acc[0][cf] = __builtin_amdgcn_mfma_f32_16x16x32_bf16(a0, b, acc[0][cf], 0, 0, 0);
            acc[1][cf] = __builtin_amdgcn_mfma_f32_16x16x32_bf16(a1, b, acc[1][cf], 0, 0, 0);
        }
        __syncthreads();
    }
#pragma unroll
    for (int rf = 0; rf < 2; rf++)
#pragma unroll
        for (int cf = 0; cf < 4; cf++)
#pragma unroll
            for (int i = 0; i < 4; i++) {
                int row = rowBase + strip + rf * 16 + (l >> 4) * 4 + i;
                int col = colBase + cf * 16 + (l & 15);
                if (row < M) Cb[(size_t)row * 256 + col] = f2bf(acc[rf][cf][i]);
            }
}

// ---------------- per-(node,head) attention dots (bf16 xw) ----------------
template <int H, int C>
__global__ void k_sd(const unsigned short* __restrict__ xwb, const float* __restrict__ a_src,
                     const float* __restrict__ a_dst, float* __restrict__ s,
                     float* __restrict__ dv) {
    int gtid = blockIdx.x * 256 + threadIdx.x;
    int wid = gtid >> 6;
    int lane = threadIdx.x & 63;
    if (wid >= NN * H) return;
    int n = wid / H, h = wid % H;
    const unsigned short* base = xwb + (size_t)n * H * C + h * C;
    float vs = 0.f, vd = 0.f;
    for (int c = lane; c < C; c += 64) {
        float v = bf2f(base[c]);
        vs += v * a_src[h * C + c];
        vd += v * a_dst[h * C + c];
    }
    for (int o = 32; o; o >>= 1) { vs += __shfl_down(vs, o); vd += __shfl_down(vd, o); }
    if (lane == 0) { s[wid] = vs; dv[wid] = vd; }
}

// ------- layer-1 aggregation: reg softmax + staged unrolled accumulate -------
__global__ void k_agg1(const unsigned short* __restrict__ xwb, const float* __restrict__ s,
                       const float* __restrict__ dvec, const int* __restrict__ offs,
                       const int* __restrict__ csrc, const float* __restrict__ b1,
                       unsigned short* __restrict__ h1b) {
    __shared__ __align__(16) uint2 ebuf[2][64];
    __shared__ float tmp[128];
    int n = blockIdx.x;
    int h = threadIdx.x >> 6;
    int lane = threadIdx.x & 63;
    int start = offs[n], end = offs[n + 1];
    int deg = end - start;
    float dn = dvec[n * 2 + h];
    float denom, acc0 = 0.f, acc1 = 0.f;

    if (deg <= 64) {
        int sn = 0; float e = -1e30f;
        if (lane < deg) {
            sn = csrc[start + lane];
            e = s[sn * 2 + h] + dn;
            e = (e > 0.f) ? e : 0.2f * e;
        }
        float m = e;
        for (int o = 32; o; o >>= 1) m = fmaxf(m, __shfl_xor(m, o));
        float w = (lane < deg) ? expf(e - m) : 0.f;
        denom = w;
        for (int o = 32; o; o >>= 1) denom += __shfl_xor(denom, o);
        ebuf[h][lane] = make_uint2(__float_as_uint(w), (unsigned)sn);
        __syncthreads();
        int cr = (deg + 3) & ~3;
        for (int j0 = 0; j0 < cr; j0 += 4) {
            uint4 q0 = *(const uint4*)&ebuf[h][j0];
            uint4 q1 = *(const uint4*)&ebuf[h][j0 + 2];
            const unsigned short* g0 = xwb + (size_t)q0.y * 256 + h * 128 + lane;
            const unsigned short* g1 = xwb + (size_t)q0.w * 256 + h * 128 + lane;
            const unsigned short* g2 = xwb + (size_t)q1.y * 256 + h * 128 + lane;
            const unsigned short* g3 = xwb + (size_t)q1.w * 256 + h * 128 + lane;
            float w0 = __uint_as_float(q0.x), w1 = __uint_as_float(q0.z);
            float w2 = __uint_as_float(q1.x), w3 = __uint_as_float(q1.z);
            acc0 += w0 * bf2f(g0[0]) + w1 * bf2f(g1[0]) + w2 * bf2f(g2[0]) + w3 * bf2f(g3[0]);
            acc1 += w0 * bf2f(g0[64]) + w1 * bf2f(g1[64]) + w2 * bf2f(g2[64]) + w3 * bf2f(g3[64]);
        }
    } else {
        float m = -1e30f;
        for (int i = start + lane; i < end; i += 64) {
            int sn = csrc[i];
            float e = s[sn * 2 + h] + dn;
            e = (e > 0.f) ? e : 0.2f * e;
            m = fmaxf(m, e);
        }
        for (int o = 32; o; o >>= 1) m = fmaxf(m, __shfl_xor(m, o));
        denom = 0.f;
        for (int ch = start; ch < end; ch += 64) {
            int i = ch + lane;
            int sn = 0; float w = 0.f;
            if (i < end) {
                sn = csrc[i];
                float e = s[sn * 2 + h] + dn;
                e = (e > 0.f) ? e : 0.2f * e;
                w = expf(e - m);
            }
            float dsum = w;
            for (int o = 32; o; o >>= 1) dsum += __shfl_xor(dsum, o);
            denom += dsum;
            ebuf[h][lane] = make_uint2(__float_as_uint(w), (unsigned)sn);
            __syncthreads();
            int cnt = min(64, end - ch);
            int cr = (cnt + 3) & ~3;
            for (int j0 = 0; j0 < cr; j0 += 4) {
                uint4 q0 = *(const uint4*)&ebuf[h][j0];
                uint4 q1 = *(const uint4*)&ebuf[h][j0 + 2];
                const unsigned short* g0 = xwb + (size_t)q0.y * 256 + h * 128 + lane;
                const unsigned short* g1 = xwb + (size_t)q0.w * 256 + h * 128 + lane;
                const unsigned short* g2 = xwb + (size_t)q1.y * 256 + h * 128 + lane;
                const unsigned short* g3 = xwb + (size_t)q1.w * 256 + h * 128 + lane;
                float w0 = __uint_as_float(q0.x), w1 = __uint_as_float(q0.z);
                float w2 = __uint_as_float(q1.x), w3 = __uint_as_float(q1.z);
                acc0 += w0 * bf2f(g0[0]) + w1 * bf2f(g1[0]) + w2 * bf2f(g2[0]) + w3 * bf2f(g3[0]);
                acc1 += w0 * bf2f(g0[64]) + w1 * bf2f(g1[64]) + w2 * bf2f(g2[64]) + w3 * bf2f(g3[64]);
            }
            __syncthreads();
        }
    }
    float inv = 1.f / (denom + 1e-16f);
    acc0 *= inv; acc1 *= inv;
    if (h == 1) { tmp[lane] = acc0; tmp[64 + lane] = acc1; }
    __syncthreads();
    if (h == 0) {
        h1b[(size_t)n * 128 + lane] =
            f2bf(sigmoidf_(0.5f * (acc0 + tmp[lane]) + b1[lane]));
        h1b[(size_t)n * 128 + 64 + lane] =
            f2bf(sigmoidf_(0.5f * (acc1 + tmp[64 + lane]) + b1[64 + lane]));
    }
}

// ------- layer-2 aggregation: reg softmax + staged unrolled accumulate + pool -------
__global__ void k_agg2(const unsigned short* __restrict__ xwb, const float* __restrict__ s,
                       const float* __restrict__ dvec, const int* __restrict__ offs,
                       const int* __restrict__ csrc, const float* __restrict__ b2,
                       const int* __restrict__ batch, float* __restrict__ gsum) {
    __shared__ __align__(16) uint2 ebuf[4][64];
    __shared__ float tmp[4][64];
    int n = blockIdx.x;
    int h = threadIdx.x >> 6;
    int lane = threadIdx.x & 63;
    int start = offs[n], end = offs[n + 1];
    int deg = end - start;
    float dn = dvec[n * 4 + h];
    float denom, acc = 0.f;

    if (deg <= 64) {
        int sn = 0; float e = -1e30f;
        if (lane < deg) {
            sn = csrc[start + lane];
            e = s[sn * 4 + h] + dn;
            e = (e > 0.f) ? e : 0.2f * e;
        }
        float m = e;
        for (int o = 32; o; o >>= 1) m = fmaxf(m, __shfl_xor(m, o));
        float w = (lane < deg) ? expf(e - m) : 0.f;
        denom = w;
        for (int o = 32; o; o >>= 1) denom += __shfl_xor(denom, o);
        ebuf[h][lane] = make_uint2(__float_as_uint(w), (unsigned)sn);
        __syncthreads();
        int cr = (deg + 3) & ~3;
        for (int j0 = 0; j0 < cr; j0 += 4) {
            uint4 q0 = *(const uint4*)&ebuf[h][j0];
            uint4 q1 = *(const uint4*)&ebuf[h][j0 + 2];
            float w0 = __uint_as_float(q0.x), w1 = __uint_as_float(q0.z);
            float w2 = __uint_as_float(q1.x), w3 = __uint_as_float(q1.z);
            acc += w0 * bf2f(xwb[(size_t)q0.y * 256 + h * 64 + lane])
                 + w1 * bf2f(xwb[(size_t)q0.w * 256 + h * 64 + lane])
                 + w2 * bf2f(xwb[(size_t)q1.y * 256 + h * 64 + lane])
                 + w3 * bf2f(xwb[(size_t)q1.w * 256 + h * 64 + lane]);
        }
    } else {
        float m = -1e30f;
        for (int i = start + lane; i < end; i += 64) {
            int sn = csrc[i];
            float e = s[sn * 4 + h] + dn;
            e = (e > 0.f) ? e : 0.2f * e;
            m = fmaxf(m, e);
        }
        for (int o = 32; o; o >>= 1) m = fmaxf(m, __shfl_xor(m, o));
        denom = 0.f;
        for (int ch = start; ch < end; ch += 64) {
            int i = ch + lane;
            int sn = 0; float w = 0.f;
            if (i < end) {
                sn = csrc[i];
                float e = s[sn * 4 + h] + dn;
                e = (e > 0.f) ? e : 0.2f * e;
                w = expf(e - m);
            }
            float dsum = w;
            for (int o = 32; o; o >>= 1) dsum += __shfl_xor(dsum, o);
            denom += dsum;
            ebuf[h][lane] = make_uint2(__float_as_uint(w), (unsigned)sn);
            __syncthreads();
            int cnt = min(64, end - ch);
            int cr = (cnt + 3) & ~3;
            for (int j0 = 0; j0 < cr; j0 += 4) {
                uint4 q0 = *(const uint4*)&ebuf[h][j0];
                uint4 q1 = *(const uint4*)&ebuf[h][j0 + 2];
                float w0 = __uint_as_float(q0.x), w1 = __uint_as_float(q0.z);
                float w2 = __uint_as_float(q1.x), w3 = __uint_as_float(q1.z);
                acc += w0 * bf2f(xwb[(size_t)q0.y * 256 + h * 64 + lane])
                     + w1 * bf2f(xwb[(size_t)q0.w * 256 + h * 64 + lane])
                     + w2 * bf2f(xwb[(size_t)q1.y * 256 + h * 64 + lane])
                     + w3 * bf2f(xwb[(size_t)q1.w * 256 + h * 64 + lane]);
            }
            __syncthreads();
        }
    }
    tmp[h][lane] = acc / (denom + 1e-16f);
    __syncthreads();
    if (h == 0) {
        float v = 0.25f * (tmp[0][lane] + tmp[1][lane] + tmp[2][lane] + tmp[3][lane]) + b2[lane];
        atomicAdd(&gsum[batch[n] * 64 + lane], sigmoidf_(v));
    }
}

// ---------------- final ----------------
__global__ void k_final(const float* __restrict__ gsum, const float* __restrict__ lw,
                        const float* __restrict__ lb, float* __restrict__ out) {
    int g = blockIdx.x;
    int lane = threadIdx.x;
    float v = gsum[g * 64 + lane] * lw[lane];
    for (int o = 32; o; o >>= 1) v += __shfl_down(v, o);
    if (lane == 0) out[g] = sigmoidf_(v + lb[0]);
}

// ---------------- launch ----------------
extern "C" void kernel_launch(void* const* d_in, const int* in_sizes, int n_in,
                              void* d_out, int out_size, void* d_ws, size_t ws_size,
                              hipStream_t stream) {
    const int* x   = (const int*)d_in[0];
    const int* ei  = (const int*)d_in[1];
    const int* bat = (const int*)d_in[3];
    const float* e0 = (const float*)d_in[4];
    const float* e1 = (const float*)d_in[5];
    const float* e2 = (const float*)d_in[6];
    const float* e3 = (const float*)d_in[7];
    const float* e4 = (const float*)d_in[8];
    const float* e5 = (const float*)d_in[9];
    const float* W1 = (const float*)d_in[10];
    const float* as1 = (const float*)d_in[11];
    const float* ad1 = (const float*)d_in[12];
    const float* b1 = (const float*)d_in[13];
    const float* W2 = (const float*)d_in[14];
    const float* as2 = (const float*)d_in[15];
    const float* ad2 = (const float*)d_in[16];
    const float* b2 = (const float*)d_in[17];
    const float* lw = (const float*)d_in[18];
    const float* lb = (const float*)d_in[19];
    float* out = (float*)d_out;

    char* base = (char*)d_ws;
    size_t off = 0;
    auto alloc = [&](size_t bytes) {
        size_t o = off;
        off = (off + bytes + 255) & ~(size_t)255;
        return o;
    };
    unsigned short* xwb = (unsigned short*)(base + alloc((size_t)NN * 256 * 2));
    unsigned short* h1b = (unsigned short*)(base + alloc((size_t)NN * 128 * 2));
    float* sbuf = (float*)(base + alloc((size_t)NN * 4 * 4));
    float* dbuf = (float*)(base + alloc((size_t)NN * 4 * 4));
    float* gsum = (float*)(base + alloc((size_t)GG * 64 * 4));
    int* deg  = (int*)(base + alloc((size_t)NN * 4));
    int* offs = (int*)(base + alloc((size_t)(NN + 1) * 4));
    int* cur  = (int*)(base + alloc((size_t)NN * 4));
    int* csrc = (int*)(base + alloc((size_t)ETOT * 4));
    int* bsum = (int*)(base + alloc((size_t)512 * 4));
    unsigned short* ebf = (unsigned short*)(base + alloc((size_t)50 * 64 * 2));
    unsigned short* Wt1 = (unsigned short*)(base + alloc((size_t)384 * 256 * 2));
    unsigned short* Wt2 = (unsigned short*)(base + alloc((size_t)128 * 256 * 2));

    const int nb = (NN + 255) / 256;  // 391

    k_zero<<<nb, 256, 0, stream>>>(deg, cur, gsum);
    k_prep_emb<<<(50 * 64 + 255) / 256, 256, 0, stream>>>(e0, e1, e2, e3, e4, e5, ebf);
    k_prep_w<12><<<(12 * 16 * 64 + 255) / 256, 256, 0, stream>>>(W1, Wt1);
    k_prep_w<4><<<(4 * 16 * 64 + 255) / 256, 256, 0, stream>>>(W2, Wt2);
    k_hist<<<(ETOT + 255) / 256, 256, 0, stream>>>(ei, deg);
    k_scan1<<<nb, 256, 0, stream>>>(deg, offs, bsum);
    k_scan2<<<1, 64, 0, stream>>>(bsum, nb, offs);
    k_scan3<<<nb, 256, 0, stream>>>(offs, bsum);
    k_scatter<<<(ETOT + 255) / 256, 256, 0, stream>>>(ei, offs, cur, csrc);

    // layer 1
    {
        dim3 grid(4, (NN + 127) / 128);
        k_gemm_mfma<0, 12><<<grid, 256, 0, stream>>>(x, ebf, nullptr, Wt1, xwb, NN);
    }
    k_sd<2, 128><<<(NN * 2 * 64) / 256, 256, 0, stream>>>(xwb, as1, ad1, sbuf, dbuf);
    k_agg1<<<NN, 128, 0, stream>>>(xwb, sbuf, dbuf, offs, csrc, b1, h1b);

    // layer 2
    {
        dim3 grid(4, (NN + 127) / 128);
        k_gemm_mfma<1, 4><<<grid, 256, 0, stream>>>(x, ebf, h1b, Wt2, xwb, NN);
    }
    k_sd<4, 64><<<(NN * 4 * 64) / 256, 256, 0, stream>>>(xwb, as2, ad2, sbuf, dbuf);
    k_agg2<<<NN, 256, 0, stream>>>(xwb, sbuf, dbuf, offs, csrc, b2, bat, gsum);

    // final
    k_final<<<GG, 64, 0, stream>>>(gsum, lw, lb, out);
}